// Round 14
// baseline (757.885 us; speedup 1.0000x reference)
//
#include <hip/hip_runtime.h>
#include <hip/hip_bf16.h>

#define CDIV(a, b) (((a) + (b) - 1) / (b))

typedef __attribute__((ext_vector_type(8))) __bf16 bf16x8;
typedef __attribute__((ext_vector_type(2))) __bf16 bf16x2;
typedef __attribute__((ext_vector_type(4))) float f32x4;

__device__ __forceinline__ float bf2f(unsigned short u) {
  union { unsigned int i; float f; } c; c.i = ((unsigned int)u) << 16; return c.f;
}
__device__ __forceinline__ unsigned short f2bf(float f) {
  union { float f; unsigned int i; } c; c.f = f;
  unsigned int r = c.i + 0x7fffu + ((c.i >> 16) & 1u);
  return (unsigned short)(r >> 16);
}
__device__ __forceinline__ unsigned int cvt2(float a, float b) {
  bf16x2 v; v[0] = (__bf16)a; v[1] = (__bf16)b;
  union { bf16x2 v; unsigned int u; } c; c.v = v; return c.u;
}
__device__ __forceinline__ unsigned short cvt1(float a) {
  __bf16 b = (__bf16)a;
  union { __bf16 b; unsigned short u; } c; c.b = b; return c.u;
}
// packed hi/lo (u32 = hi | lo<<16) -- Y self-term only
__device__ __forceinline__ float dec1(unsigned int u) {
  union { unsigned int i; float f; } a, b;
  a.i = u << 16; b.i = u & 0xffff0000u;
  return a.f + b.f;
}
__device__ __forceinline__ unsigned int packhl(float v) {
  __bf16 h = (__bf16)v;
  float hf = (float)h;
  __bf16 l = (__bf16)(v - hf);
  bf16x2 p; p[0] = h; p[1] = l;
  union { bf16x2 v; unsigned int u; } c; c.v = p; return c.u;
}

// ---- dtype detector ----
__global__ void k_detect(const unsigned short* __restrict__ xq, int nsamp, int* __restrict__ flagp) {
  __shared__ float sm[256];
  int t = threadIdx.x;
  float mx = 0.f;
  for (int i = t; i < nsamp; i += 256) {
    float v = bf2f(xq[i]);
    if (!(v == v)) v = 1e30f;
    mx = fmaxf(mx, fabsf(v));
  }
  sm[t] = mx; __syncthreads();
  for (int o = 128; o > 0; o >>= 1) {
    if (t < o) sm[t] = fmaxf(sm[t], sm[t + o]);
    __syncthreads();
  }
  if (t == 0) *flagp = (sm[0] > 1e6f) ? 1 : 0;
}

// ---- 7 small fp32 conversions in one dispatch ----
__global__ void k_cvt7(const void* p0, const void* p1, const void* p2, const void* p3,
                       const void* p4, const void* p5, const void* p6,
                       float* d0, float* d1, float* d2, float* d3,
                       float* d4, float* d5, float* d6, const int* __restrict__ flagp) {
  int b = blockIdx.x, t = threadIdx.x;
  const void* s = 0; float* d = 0; int n = 256;
  switch (b) {
    case 0: s = p0; d = d0; break;
    case 1: s = p1; d = d1; break;
    case 2: s = p2; d = d2; break;
    case 3: s = p3; d = d3; break;
    case 4: s = p4; d = d4; break;
    case 5: s = p5; d = d5; break;
    default: s = p6; d = d6; n = 1; break;
  }
  if (t < n) d[t] = (*flagp) ? ((const float*)s)[t] : bf2f(((const unsigned short*)s)[t]);
}

// ---- all 8 weight transposes in one dispatch ----
__global__ void k_whall(const void* W0, const void* W1, const void* W2, const void* W3,
                        const void* W4, const void* W5, const void* W6, const void* W7,
                        unsigned short* o0, unsigned short* o1, unsigned short* o2,
                        unsigned short* o3, unsigned short* o4, unsigned short* o5,
                        unsigned short* o6, unsigned short* o7, const int* __restrict__ flagp) {
  int b = blockIdx.x;
  const void* W; unsigned short* Bt; int K;
  if (b < 256) {
    K = 128;
    if (b < 128) { W = W0; Bt = o0; } else { W = W1; Bt = o1; b -= 128; }
  } else {
    K = 256;
    int m = (b - 256) >> 8;
    b = (b - 256) & 255;
    switch (m) {
      case 0: W = W2; Bt = o2; break;
      case 1: W = W3; Bt = o3; break;
      case 2: W = W4; Bt = o4; break;
      case 3: W = W5; Bt = o5; break;
      case 4: W = W6; Bt = o6; break;
      default: W = W7; Bt = o7; break;
    }
  }
  int i = b * 256 + threadIdx.x;
  if (i >= K * 256) return;
  int k = i >> 8, n = i & 255;
  float v = (*flagp) ? ((const float*)W)[i] : bf2f(((const unsigned short*)W)[i]);
  Bt[(size_t)n * K + k] = f2bf(v);
}

// ---- x -> bf16 plane ----
__global__ void k_xbf16(const void* __restrict__ x, unsigned short* __restrict__ Xb, int n,
                        const int* __restrict__ flagp) {
  int i = blockIdx.x * 256 + threadIdx.x;
  if (i >= n) return;
  float v = (*flagp) ? ((const float*)x)[i] : bf2f(((const unsigned short*)x)[i]);
  Xb[i] = f2bf(v);
}

__global__ void k_zero_i32(int* p, int n) {
  int i = blockIdx.x * 256 + threadIdx.x;
  if (i < n) p[i] = 0;
}

// ---------------- CSR build ----------------
__global__ void k_deg(const int* __restrict__ dst, int* __restrict__ deg, int E) {
  int e = blockIdx.x * 256 + threadIdx.x;
  if (e < E) atomicAdd(&deg[dst[e]], 1);
}
__global__ void k_scan1(const int* __restrict__ in, int* __restrict__ out, int* __restrict__ bsums, int n) {
  __shared__ int sh[256];
  int t = threadIdx.x, i = blockIdx.x * 256 + t;
  int v = (i < n) ? in[i] : 0;
  sh[t] = v; __syncthreads();
  for (int o = 1; o < 256; o <<= 1) {
    int add = (t >= o) ? sh[t - o] : 0;
    __syncthreads();
    sh[t] += add;
    __syncthreads();
  }
  if (i < n) out[i] = sh[t] - v;
  if (t == 255) bsums[blockIdx.x] = sh[255];
}
__global__ void k_scan2(int* bsums, int nb) {
  __shared__ int sh[256];
  int t = threadIdx.x;
  int v = (t < nb) ? bsums[t] : 0;
  sh[t] = v; __syncthreads();
  for (int o = 1; o < 256; o <<= 1) {
    int add = (t >= o) ? sh[t - o] : 0;
    __syncthreads();
    sh[t] += add;
    __syncthreads();
  }
  if (t < nb) bsums[t] = sh[t] - v;
}
__global__ void k_scan3(int* offs, int* cur, const int* bsums, int n, int etot) {
  int i = blockIdx.x * 256 + threadIdx.x;
  if (i < n) {
    int v = offs[i] + bsums[blockIdx.x];
    offs[i] = v;
    cur[i] = v;
  }
  if (i == 0) offs[n] = etot;
}
__global__ void k_fill(const int* __restrict__ dst, const int* __restrict__ src,
                       int* __restrict__ cursor, int* __restrict__ csr_src, int E) {
  int e = blockIdx.x * 256 + threadIdx.x;
  if (e >= E) return;
  int pos = atomicAdd(&cursor[dst[e]], 1);
  csr_src[pos] = src[e];
}
// ---- wave-parallel bitonic sort per node ----
__global__ void k_sortw(const int* __restrict__ offs, int* __restrict__ csr, int n) {
  int w = threadIdx.x >> 6, lane = threadIdx.x & 63;
  int v = blockIdx.x * 4 + w;
  if (v >= n) return;
  int s = offs[v], e = offs[v + 1];
  int deg = e - s;
  if (deg <= 1) return;
  if (deg > 64) {
    if (lane == 0) {
      for (int i = s + 1; i < e; ++i) {
        int key = csr[i], j = i - 1;
        while (j >= s && csr[j] > key) { csr[j + 1] = csr[j]; --j; }
        csr[j + 1] = key;
      }
    }
    return;
  }
  int val = (lane < deg) ? csr[s + lane] : 0x7fffffff;
#pragma unroll
  for (int k = 2; k <= 64; k <<= 1) {
    bool dir = (lane & k) == 0;
#pragma unroll
    for (int j = k >> 1; j > 0; j >>= 1) {
      int p = __shfl_xor(val, j, 64);
      bool lower = (lane & j) == 0;
      val = (lower == dir) ? min(val, p) : max(val, p);
    }
  }
  if (lane < deg) csr[s + lane] = val;
}

// ---- fused agg epilogue: H[v] = act(Y[v] + mean_u Z[u] + b); H out bf16 ----
__global__ void k_aggfuse(const unsigned int* __restrict__ Yp, const unsigned short* __restrict__ Zh,
                          const int* __restrict__ offs, const int* __restrict__ csr,
                          const float* __restrict__ bias, int relu,
                          unsigned short* __restrict__ Hb) {
  int w = threadIdx.x >> 6, lane = threadIdx.x & 63;
  int v = blockIdx.x * 4 + w;
  int c4 = lane * 4;
  uint4 yq = *(const uint4*)&Yp[(size_t)v * 256 + c4];
  int s = offs[v], e = offs[v + 1];
  float a0 = 0.f, a1 = 0.f, a2 = 0.f, a3 = 0.f;
  int i = s;
  for (; i + 2 <= e; i += 2) {
    uint2 z0 = *(const uint2*)&Zh[(size_t)csr[i] * 256 + c4];
    uint2 z1 = *(const uint2*)&Zh[(size_t)csr[i + 1] * 256 + c4];
    a0 += bf2f((unsigned short)z0.x) + bf2f((unsigned short)z1.x);
    a1 += bf2f((unsigned short)(z0.x >> 16)) + bf2f((unsigned short)(z1.x >> 16));
    a2 += bf2f((unsigned short)z0.y) + bf2f((unsigned short)z1.y);
    a3 += bf2f((unsigned short)(z0.y >> 16)) + bf2f((unsigned short)(z1.y >> 16));
  }
  if (i < e) {
    uint2 z0 = *(const uint2*)&Zh[(size_t)csr[i] * 256 + c4];
    a0 += bf2f((unsigned short)z0.x);
    a1 += bf2f((unsigned short)(z0.x >> 16));
    a2 += bf2f((unsigned short)z0.y);
    a3 += bf2f((unsigned short)(z0.y >> 16));
  }
  float inv = 1.f / fmaxf((float)(e - s), 1.f);
  float4 bv = *(const float4*)&bias[c4];
  float r0 = dec1(yq.x) + a0 * inv + bv.x;
  float r1 = dec1(yq.y) + a1 * inv + bv.y;
  float r2 = dec1(yq.z) + a2 * inv + bv.z;
  float r3 = dec1(yq.w) + a3 * inv + bv.w;
  if (relu) {
    r0 = fmaxf(r0, 0.f); r1 = fmaxf(r1, 0.f);
    r2 = fmaxf(r2, 0.f); r3 = fmaxf(r3, 0.f);
  }
  uint2 o;
  o.x = cvt2(r0, r1);
  o.y = cvt2(r2, r3);
  *(uint2*)&Hb[(size_t)v * 256 + c4] = o;
}

// ---- layer MFMA GEMM: A bf16 plane, dual B; Y packed (nt<2) / Zh bf16 (nt>=2) ----
__global__ __launch_bounds__(256) void gemm2(
    const unsigned short* __restrict__ Ab, int K,
    const unsigned short* __restrict__ B1h, const unsigned short* __restrict__ B2h,
    int M, unsigned int* __restrict__ O1p, unsigned short* __restrict__ O2b) {
  __shared__ unsigned short sAh[128 * 40], sBh[128 * 40];
  int t = threadIdx.x;
  int mt = blockIdx.x >> 2, nt = blockIdx.x & 3;
  int m0 = mt * 128;
  const unsigned short* Bh = (nt < 2) ? B1h : B2h;
  int n0 = (nt & 1) * 128;
  int wid = t >> 6, lane = t & 63;
  int wr = (wid >> 1) * 64, wc = (wid & 1) * 64;
  int quad = lane >> 4, lrow = lane & 15;

  f32x4 acc[4][4];
  const f32x4 z4 = {0.f, 0.f, 0.f, 0.f};
#pragma unroll
  for (int i = 0; i < 4; ++i)
#pragma unroll
    for (int j = 0; j < 4; ++j) acc[i][j] = z4;

  int sr = t >> 2;
  int c8 = (t & 3) * 8;

  for (int k0 = 0; k0 < K; k0 += 32) {
#pragma unroll
    for (int rep = 0; rep < 2; ++rep) {
      int r = sr + rep * 64;
      int arow = m0 + r; if (arow >= M) arow = M - 1;
      *(uint4*)&sAh[r * 40 + c8] = *(const uint4*)&Ab[(size_t)arow * K + k0 + c8];
      *(uint4*)&sBh[r * 40 + c8] = *(const uint4*)&Bh[(size_t)(n0 + r) * K + k0 + c8];
    }
    __syncthreads();
    bf16x8 ah[4], bh[4];
#pragma unroll
    for (int i = 0; i < 4; ++i) {
      ah[i] = *(const bf16x8*)&sAh[(wr + i * 16 + lrow) * 40 + quad * 8];
      bh[i] = *(const bf16x8*)&sBh[(wc + i * 16 + lrow) * 40 + quad * 8];
    }
#pragma unroll
    for (int i = 0; i < 4; ++i)
#pragma unroll
      for (int j = 0; j < 4; ++j)
        acc[i][j] = __builtin_amdgcn_mfma_f32_16x16x32_bf16(ah[i], bh[j], acc[i][j], 0, 0, 0);
    __syncthreads();
  }

#pragma unroll
  for (int j = 0; j < 4; ++j) {
    int gc = n0 + wc + j * 16 + lrow;
#pragma unroll
    for (int i = 0; i < 4; ++i) {
#pragma unroll
      for (int rr = 0; rr < 4; ++rr) {
        int gr = m0 + wr + i * 16 + quad * 4 + rr;
        if (gr < M) {
          float v = acc[i][j][rr];
          size_t idx = (size_t)gr * 256 + gc;
          if (nt < 2) O1p[idx] = packhl(v);
          else        O2b[idx] = cvt1(v);
        }
      }
    }
  }
}

// ---- predictor GEMM-1 v2: gather E once into LDS, two n-half passes ----
// Z1 = relu((H[s]*H[d])@Wp1^T + b). grid.x = CDIV(M,128), block 256.
#define SE_STRIDE 264
__global__ __launch_bounds__(256) void gemm_pred1(
    const unsigned short* __restrict__ Hb,
    const int* __restrict__ ps, const int* __restrict__ pd,
    const int* __restrict__ ns, const int* __restrict__ nd,
    int nPos, const unsigned short* __restrict__ Bh,
    const float* __restrict__ bias, int M, unsigned short* __restrict__ O1b) {
  __shared__ unsigned short sE[128 * SE_STRIDE];   // full-width gathered E rows
  __shared__ unsigned short sBh[128 * 40];
  int t = threadIdx.x;
  int m0 = blockIdx.x * 128;
  int wid = t >> 6, lane = t & 63;
  int wr = (wid >> 1) * 64, wc = (wid & 1) * 64;
  int quad = lane >> 4, lrow = lane & 15;

  // ---- phase 0: gather + decode 128 E rows (once) ----
  // uint4 = 8 shorts; 16 iterations x 8 shorts = 128 columns per thread-half.
  {
    int r = t >> 1;                 // 0..127
    int ch = (t & 1) * 128;         // column half
    int arow = m0 + r; if (arow >= M) arow = M - 1;
    int s, d;
    if (arow < nPos) { s = ps[arow]; d = pd[arow]; }
    else             { s = ns[arow - nPos]; d = nd[arow - nPos]; }
    const unsigned short* Hs = &Hb[(size_t)s * 256 + ch];
    const unsigned short* Hd = &Hb[(size_t)d * 256 + ch];
    unsigned short* se = &sE[r * SE_STRIDE + ch];
#pragma unroll
    for (int q = 0; q < 16; ++q) {
      uint4 hs = *(const uint4*)(Hs + q * 8);
      uint4 hd = *(const uint4*)(Hd + q * 8);
      uint4 o;
      o.x = cvt2(bf2f((unsigned short)hs.x) * bf2f((unsigned short)hd.x),
                 bf2f((unsigned short)(hs.x >> 16)) * bf2f((unsigned short)(hd.x >> 16)));
      o.y = cvt2(bf2f((unsigned short)hs.y) * bf2f((unsigned short)hd.y),
                 bf2f((unsigned short)(hs.y >> 16)) * bf2f((unsigned short)(hd.y >> 16)));
      o.z = cvt2(bf2f((unsigned short)hs.z) * bf2f((unsigned short)hd.z),
                 bf2f((unsigned short)(hs.z >> 16)) * bf2f((unsigned short)(hd.z >> 16)));
      o.w = cvt2(bf2f((unsigned short)hs.w) * bf2f((unsigned short)hd.w),
                 bf2f((unsigned short)(hs.w >> 16)) * bf2f((unsigned short)(hd.w >> 16)));
      *(uint4*)(se + q * 8) = o;
    }
  }
  __syncthreads();

  int sr = t >> 2;
  int c8 = (t & 3) * 8;

  // ---- two n-half passes ----
  for (int nt = 0; nt < 2; ++nt) {
    int n0 = nt * 128;
    f32x4 acc[4][4];
    const f32x4 z4 = {0.f, 0.f, 0.f, 0.f};
#pragma unroll
    for (int i = 0; i < 4; ++i)
#pragma unroll
      for (int j = 0; j < 4; ++j) acc[i][j] = z4;

    for (int k0 = 0; k0 < 256; k0 += 32) {
#pragma unroll
      for (int rep = 0; rep < 2; ++rep) {
        int r = sr + rep * 64;
        *(uint4*)&sBh[r * 40 + c8] = *(const uint4*)&Bh[(size_t)(n0 + r) * 256 + k0 + c8];
      }
      __syncthreads();
      bf16x8 ah[4], bh[4];
#pragma unroll
      for (int i = 0; i < 4; ++i) {
        ah[i] = *(const bf16x8*)&sE[(wr + i * 16 + lrow) * SE_STRIDE + k0 + quad * 8];
        bh[i] = *(const bf16x8*)&sBh[(wc + i * 16 + lrow) * 40 + quad * 8];
      }
#pragma unroll
      for (int i = 0; i < 4; ++i)
#pragma unroll
        for (int j = 0; j < 4; ++j)
          acc[i][j] = __builtin_amdgcn_mfma_f32_16x16x32_bf16(ah[i], bh[j], acc[i][j], 0, 0, 0);
      __syncthreads();
    }

#pragma unroll
    for (int j = 0; j < 4; ++j) {
      int gc = n0 + wc + j * 16 + lrow;
      float bv = bias[gc];
#pragma unroll
      for (int i = 0; i < 4; ++i) {
#pragma unroll
        for (int rr = 0; rr < 4; ++rr) {
          int gr = m0 + wr + i * 16 + quad * 4 + rr;
          if (gr < M) {
            float v = fmaxf(acc[i][j][rr] + bv, 0.f);
            O1b[(size_t)gr * 256 + gc] = cvt1(v);
          }
        }
      }
    }
  }
}

// ---- predictor GEMM-2 + fused dot (atomic-free, two partial planes) ----
__global__ __launch_bounds__(256) void gemm_dot(
    const unsigned short* __restrict__ Ab,
    const unsigned short* __restrict__ Bh, const float* __restrict__ bias,
    const float* __restrict__ wp3, int M, float* __restrict__ P0, float* __restrict__ P1) {
  __shared__ unsigned short sAh[128 * 40], sBh[128 * 40];
  __shared__ float part[128][33];
  int t = threadIdx.x;
  int mt = blockIdx.x >> 1, nt = blockIdx.x & 1;
  int m0 = mt * 128;
  int n0 = nt * 128;
  int wid = t >> 6, lane = t & 63;
  int wr = (wid >> 1) * 64, wc = (wid & 1) * 64;
  int quad = lane >> 4, lrow = lane & 15;

  f32x4 acc[4][4];
  const f32x4 z4 = {0.f, 0.f, 0.f, 0.f};
#pragma unroll
  for (int i = 0; i < 4; ++i)
#pragma unroll
    for (int j = 0; j < 4; ++j) acc[i][j] = z4;

  int sr = t >> 2;
  int c8 = (t & 3) * 8;

  for (int k0 = 0; k0 < 256; k0 += 32) {
#pragma unroll
    for (int rep = 0; rep < 2; ++rep) {
      int r = sr + rep * 64;
      int arow = m0 + r; if (arow >= M) arow = M - 1;
      *(uint4*)&sAh[r * 40 + c8] = *(const uint4*)&Ab[(size_t)arow * 256 + k0 + c8];
      *(uint4*)&sBh[r * 40 + c8] = *(const uint4*)&Bh[(size_t)(n0 + r) * 256 + k0 + c8];
    }
    __syncthreads();
    bf16x8 ah[4], bh[4];
#pragma unroll
    for (int i = 0; i < 4; ++i) {
      ah[i] = *(const bf16x8*)&sAh[(wr + i * 16 + lrow) * 40 + quad * 8];
      bh[i] = *(const bf16x8*)&sBh[(wc + i * 16 + lrow) * 40 + quad * 8];
    }
#pragma unroll
    for (int i = 0; i < 4; ++i)
#pragma unroll
      for (int j = 0; j < 4; ++j)
        acc[i][j] = __builtin_amdgcn_mfma_f32_16x16x32_bf16(ah[i], bh[j], acc[i][j], 0, 0, 0);
    __syncthreads();
  }

  int cid = (wid & 1) * 16 + lrow;
#pragma unroll
  for (int i = 0; i < 4; ++i) {
#pragma unroll
    for (int rr = 0; rr < 4; ++rr) {
      int rloc = wr + i * 16 + quad * 4 + rr;
      float s = 0.f;
#pragma unroll
      for (int j = 0; j < 4; ++j) {
        int gc = n0 + wc + j * 16 + lrow;
        float v = fmaxf(acc[i][j][rr] + bias[gc], 0.f);
        s += v * wp3[gc];
      }
      part[rloc][cid] = s;
    }
  }
  __syncthreads();
  if (t < 128) {
    int gr = m0 + t;
    if (gr < M) {
      float s = 0.f;
#pragma unroll
      for (int c = 0; c < 32; ++c) s += part[t][c];
      if (nt == 0) P0[gr] = s;
      else         P1[gr] = s;
    }
  }
}

// ---- finish: out[p] = P0[p] + P1[p] + bp3 ----
__global__ void k_finish(const float* __restrict__ P0, const float* __restrict__ P1,
                         const float* __restrict__ bp3, void* __restrict__ out,
                         int n, const int* __restrict__ flagp) {
  int p = blockIdx.x * 256 + threadIdx.x;
  if (p >= n) return;
  float r = P0[p] + P1[p] + bp3[0];
  if (*flagp) ((float*)out)[p] = r;
  else        ((unsigned short*)out)[p] = f2bf(r);
}

extern "C" void kernel_launch(void* const* d_in, const int* in_sizes, int n_in,
                              void* d_out, int out_size, void* d_ws, size_t ws_size,
                              hipStream_t stream) {
  const int N = 50000, E = 800000, P = 100000, DIN = 128, DH = 256;
  const int M2 = 2 * P;
  const void* x = d_in[0];
  const int* esrc = (const int*)d_in[1];
  const int* edst = (const int*)d_in[2];
  const int* psrc = (const int*)d_in[3];
  const int* pdst = (const int*)d_in[4];
  const int* nsrc = (const int*)d_in[5];
  const int* ndst = (const int*)d_in[6];
  const void* Ws0 = d_in[7];  const void* Wn0 = d_in[8];  const void* b0 = d_in[9];
  const void* Ws1 = d_in[10]; const void* Wn1 = d_in[11]; const void* b1 = d_in[12];
  const void* Ws2 = d_in[13]; const void* Wn2 = d_in[14]; const void* b2 = d_in[15];
  const void* Wp1 = d_in[16]; const void* bp1 = d_in[17];
  const void* Wp2 = d_in[18]; const void* bp2 = d_in[19];
  const void* Wp3 = d_in[20]; const void* bp3 = d_in[21];
  (void)in_sizes; (void)n_in; (void)out_size; (void)ws_size;

  // ---- workspace layout ----
  const size_t NH = (size_t)N * DH;
  unsigned short* Hb = (unsigned short*)d_ws;     // [N,256] bf16 (Xb for L0)
  unsigned short* Xb = Hb;
  char* reg1 = (char*)d_ws + NH * 2;
  unsigned int* Yp = (unsigned int*)reg1;                 // layers: packed u32
  unsigned short* Zh = (unsigned short*)(reg1 + NH * 4);  // layers: bf16
  unsigned short* Z1b = (unsigned short*)reg1;            // predictor: [200000,256] bf16
  float* P0 = (float*)(reg1 + (size_t)M2 * 256 * 2);
  float* P1 = P0 + M2;
  unsigned short* W16 = (unsigned short*)(P1 + M2);
  unsigned short* ws0h = W16;
  unsigned short* wn0h = ws0h + 32768;
  unsigned short* ws1h = wn0h + 32768;
  unsigned short* wn1h = ws1h + 65536;
  unsigned short* ws2h = wn1h + 65536;
  unsigned short* wn2h = ws2h + 65536;
  unsigned short* wp1h = wn2h + 65536;
  unsigned short* wp2h = wp1h + 65536;
  float* FB = (float*)(wp2h + 65536);
  float* b0f  = FB;
  float* b1f  = b0f + 256;
  float* b2f  = b1f + 256;
  float* bp1f = b2f + 256;
  float* bp2f = bp1f + 256;
  float* wp3f = bp2f + 256;
  float* bp3f = wp3f + 256;
  int* deg   = (int*)(bp3f + 4);
  int* offs  = deg + N;
  int* cur   = offs + (N + 1);
  int* bsums = cur + N;
  int* csr   = bsums + 256;
  int* flagp = csr + E;

  // ---- dtype detection ----
  k_detect<<<1, 256, 0, stream>>>((const unsigned short*)x, 8192, flagp);

  // ---- weight prep ----
  k_whall<<<256 + 6 * 256, 256, 0, stream>>>(Ws0, Wn0, Ws1, Wn1, Ws2, Wn2, Wp1, Wp2,
                                             ws0h, wn0h, ws1h, wn1h, ws2h, wn2h, wp1h, wp2h,
                                             flagp);
  k_cvt7<<<7, 256, 0, stream>>>(b0, b1, b2, bp1, bp2, Wp3, bp3,
                                b0f, b1f, b2f, bp1f, bp2f, wp3f, bp3f, flagp);

  // ---- CSR build (deterministic) ----
  int nb = CDIV(N, 256);
  k_zero_i32<<<nb, 256, 0, stream>>>(deg, N);
  k_deg<<<CDIV(E, 256), 256, 0, stream>>>(edst, deg, E);
  k_scan1<<<nb, 256, 0, stream>>>(deg, offs, bsums, N);
  k_scan2<<<1, 256, 0, stream>>>(bsums, nb);
  k_scan3<<<nb, 256, 0, stream>>>(offs, cur, bsums, N, E);
  k_fill<<<CDIV(E, 256), 256, 0, stream>>>(edst, esrc, cur, csr, E);
  k_sortw<<<CDIV(N, 4), 256, 0, stream>>>(offs, csr, N);

  const int MT = CDIV(N, 128);

  // ---- Layer 0 ----
  k_xbf16<<<CDIV(N * DIN, 256), 256, 0, stream>>>(x, Xb, N * DIN, flagp);
  gemm2<<<MT * 4, 256, 0, stream>>>(Xb, DIN, ws0h, wn0h, N, Yp, Zh);
  k_aggfuse<<<N / 4, 256, 0, stream>>>(Yp, Zh, offs, csr, b0f, 1, Hb);

  // ---- Layer 1 ----
  gemm2<<<MT * 4, 256, 0, stream>>>(Hb, DH, ws1h, wn1h, N, Yp, Zh);
  k_aggfuse<<<N / 4, 256, 0, stream>>>(Yp, Zh, offs, csr, b1f, 1, Hb);

  // ---- Layer 2 (no relu) ----
  gemm2<<<MT * 4, 256, 0, stream>>>(Hb, DH, ws2h, wn2h, N, Yp, Zh);
  k_aggfuse<<<N / 4, 256, 0, stream>>>(Yp, Zh, offs, csr, b2f, 0, Hb);

  // ---- Predictor ----
  const int G_P1 = CDIV(M2, 128);
  const int G_P2 = CDIV(M2, 128) * 2;
  gemm_pred1<<<G_P1, 256, 0, stream>>>(Hb, psrc, pdst, nsrc, ndst, P,
                                       wp1h, bp1f, M2, Z1b);
  gemm_dot<<<G_P2, 256, 0, stream>>>(Z1b, wp2h, bp2f, wp3f, M2, P0, P1);
  k_finish<<<CDIV(M2, 256), 256, 0, stream>>>(P0, P1, bp3f, d_out, M2, flagp);
}